// Round 2
// baseline (3619.491 us; speedup 1.0000x reference)
//
#include <hip/hip_runtime.h>
#include <math.h>
#include <float.h>

#define H 1080
#define W 1920
#define HWSZ (H*W)
#define NPART 25
#define NCH 26          // heatmap channels in memory (NPART+1)
#define NLIMB 26
#define KTOP 32
#define MID 10
#define RAD 12

// Tile geometry for fused blur+peak kernel
#define TH 32
#define TW 64
#define LRP 62               // padded input rows (58 needed, 4 pad via reflect-load)
#define LC  90               // input cols
#define VRR 34               // vertical-blur rows
#define VCP 93               // v cols padded to odd stride (bank spread for f64)
#define SR  34               // sm rows
#define SC  66               // sm cols (real)
#define SCP 68               // sm col stride

// Output layout (floats): px[25*32] py[25*32] score[25*32] mask[25*32] conn[26*32*32]
#define OFF_PY   800
#define OFF_SC   1600
#define OFF_MK   2400
#define OFF_CONN 3200

__device__ __constant__ int LIMBS_d[NLIMB * 2] = {
    1,8, 1,2, 1,5, 2,3, 3,4, 5,6, 6,7, 8,9, 9,10, 10,11, 8,12, 12,13, 13,14,
    1,0, 0,15, 15,16, 0,17, 0,18, 14,19, 19,20, 14,21, 11,22, 22,23, 11,24, 2,17, 5,18
};

__device__ __forceinline__ int symH(int y) {
    if (y < 0) return -1 - y;
    if (y >= H) return 2 * H - 1 - y;
    return y;
}
__device__ __forceinline__ int symW(int x) {
    if (x < 0) return -1 - x;
    if (x >= W) return 2 * W - 1 - x;
    return x;
}

// ---------------------------------------------------------------------------
// Kernel T: channels-last (H,W,26) -> 25 planar (H,W) f32 images (bit-exact copy)
// ---------------------------------------------------------------------------
__global__ __launch_bounds__(256) void transpose_k(
    const float* __restrict__ hm, float* __restrict__ planar)
{
    __shared__ float t[256][NCH + 1];   // +1 pad: stride 27 (odd) = conflict-free
    const int tid = threadIdx.x;
    const size_t base = (size_t)blockIdx.x * 256;   // pixel index
    const float* src = hm + base * NCH;
    for (int k = tid; k < 256 * NCH; k += 256) {
        t[k / NCH][k % NCH] = src[k];               // coalesced global read
    }
    __syncthreads();
    #pragma unroll
    for (int c = 0; c < NPART; c++)
        planar[(size_t)c * HWSZ + base + tid] = t[tid][c];  // coalesced write
}

// ---------------------------------------------------------------------------
// Kernel A: fused separable gaussian blur (f64 accumulation) + NMS peak detect
// on PLANAR input. grid (x-tiles, y-tiles, channel) -> same-plane L2 locality.
// ---------------------------------------------------------------------------
__global__ __launch_bounds__(256) void blur_peaks_planar(
    const float* __restrict__ planar,
    float* __restrict__ cval, int* __restrict__ cidx,
    int* __restrict__ counters, int cap)
{
    union SA {
        float  in_t[LRP][LC];   // 22.3 KB — raw tile (consumed by vertical pass)
        double smv[SR][SCP];    // 18.5 KB — overlaid after vertical pass done
    };
    __shared__ SA sa;
    __shared__ double v[VRR][VCP];      // 25.3 KB
    __shared__ double wgt[2 * RAD + 1];
    __shared__ double wsum;

    const int tid = threadIdx.x;
    const int ch  = blockIdx.z;
    const int x0  = blockIdx.x * TW;
    const int y0  = blockIdx.y * TH;
    const float* plane = planar + (size_t)ch * HWSZ;

    // gaussian weights in f64 (identical computation to round-1 exact kernel)
    if (tid < 2 * RAD + 1) {
        double t = (double)(tid - RAD) / 3.0;
        wgt[tid] = exp(-0.5 * t * t);
    }
    __syncthreads();
    if (tid == 0) {
        double s = 0.0;
        for (int i = 0; i < 2 * RAD + 1; i++) s += wgt[i];
        wsum = s;
    }
    __syncthreads();
    if (tid < 2 * RAD + 1) wgt[tid] /= wsum;

    // load input tile (coalesced planar rows, symmetric padding)
    for (int i = tid; i < LRP * LC; i += 256) {
        int r = i / LC, c = i % LC;
        int gy = symH(y0 - RAD - 1 + r);
        int gx = symW(x0 - RAD - 1 + c);
        sa.in_t[r][c] = plane[(size_t)gy * W + gx];
    }
    __syncthreads();   // also covers wgt normalization

    // vertical pass: 9 row-groups of 4 x 90 cols; sliding-window register reuse
    for (int seg = tid; seg < 9 * LC; seg += 256) {
        int c  = seg % LC;            // consecutive lanes -> consecutive cols
        int r0 = (seg / LC) * 4;
        double a0 = 0, a1 = 0, a2 = 0, a3 = 0;
        #pragma unroll
        for (int t = 0; t < 28; t++) {
            double x = (double)sa.in_t[r0 + t][c];
            if (t < 25)            a0 = fma(wgt[t],     x, a0);
            if (t >= 1 && t < 26)  a1 = fma(wgt[t - 1], x, a1);
            if (t >= 2 && t < 27)  a2 = fma(wgt[t - 2], x, a2);
            if (t >= 3)            a3 = fma(wgt[t - 3], x, a3);
        }
        v[r0][c] = a0;
        if (r0 + 1 < VRR) v[r0 + 1][c] = a1;
        if (r0 + 2 < VRR) v[r0 + 2][c] = a2;
        if (r0 + 3 < VRR) v[r0 + 3][c] = a3;
    }
    __syncthreads();   // in_t fully consumed; smv may overlay it now

    // horizontal pass: 17 col-groups of 4 x 34 rows; r fastest (bank spread)
    for (int seg = tid; seg < 17 * SR; seg += 256) {
        int r   = seg % SR;
        int cc0 = (seg / SR) * 4;
        int gy  = y0 - 1 + r;
        double a0 = 0, a1 = 0, a2 = 0, a3 = 0;
        #pragma unroll
        for (int t = 0; t < 28; t++) {
            double x = v[r][cc0 + t];
            if (t < 25)            a0 = fma(wgt[t],     x, a0);
            if (t >= 1 && t < 26)  a1 = fma(wgt[t - 1], x, a1);
            if (t >= 2 && t < 27)  a2 = fma(wgt[t - 2], x, a2);
            if (t >= 3)            a3 = fma(wgt[t - 3], x, a3);
        }
        bool rowok = (gy >= 0 && gy < H);
        {
            int cc = cc0;     if (cc < SC) { int gx = x0 - 1 + cc; sa.smv[r][cc] = (rowok && gx >= 0 && gx < W) ? a0 : 0.0; }
        }
        { int cc = cc0 + 1;   if (cc < SC) { int gx = x0 - 1 + cc; sa.smv[r][cc] = (rowok && gx >= 0 && gx < W) ? a1 : 0.0; } }
        { int cc = cc0 + 2;   if (cc < SC) { int gx = x0 - 1 + cc; sa.smv[r][cc] = (rowok && gx >= 0 && gx < W) ? a2 : 0.0; } }
        { int cc = cc0 + 3;   if (cc < SC) { int gx = x0 - 1 + cc; sa.smv[r][cc] = (rowok && gx >= 0 && gx < W) ? a3 : 0.0; } }
    }
    __syncthreads();

    // peak detection + candidate emission (original value re-read from planar copy)
    for (int i = tid; i < TH * TW; i += 256) {
        int ly = i >> 6, lx = i & 63;
        int gy = y0 + ly, gx = x0 + lx;
        if (gy >= H) continue;          // W = 30*64 exactly; only y can overhang
        double s = sa.smv[ly + 1][lx + 1];
        if (s > 0.1 &&
            s >= sa.smv[ly][lx + 1] && s >= sa.smv[ly + 2][lx + 1] &&
            s >= sa.smv[ly + 1][lx] && s >= sa.smv[ly + 1][lx + 2]) {
            float val = plane[(size_t)gy * W + gx];   // exact original bits
            int pos = atomicAdd(&counters[ch], 1);
            if (pos < cap) {
                cval[(size_t)ch * cap + pos] = val;
                cidx[(size_t)ch * cap + pos] = gy * W + gx;
            }
        }
    }
}

// ---------------------------------------------------------------------------
// Kernel A-fallback: round-1 gather version (used only if ws too small)
// ---------------------------------------------------------------------------
#define LR (TH + 2*RAD + 2)
#define VC (TW + 2*RAD + 2)
__global__ __launch_bounds__(256) void blur_peaks_gather(
    const float* __restrict__ hm,
    float* __restrict__ cval, int* __restrict__ cidx,
    int* __restrict__ counters, int cap)
{
    __shared__ float  in_t[LR][LC];
    __shared__ double v[VRR][VC];
    __shared__ double smv[SR][SC];
    __shared__ double wgt[2 * RAD + 1];
    __shared__ double wsum;

    const int tid = threadIdx.x;
    const int ch  = blockIdx.x;
    const int x0  = blockIdx.y * TW;
    const int y0  = blockIdx.z * TH;

    if (tid < 2 * RAD + 1) {
        double t = (double)(tid - RAD) / 3.0;
        wgt[tid] = exp(-0.5 * t * t);
    }
    __syncthreads();
    if (tid == 0) {
        double s = 0.0;
        for (int i = 0; i < 2 * RAD + 1; i++) s += wgt[i];
        wsum = s;
    }
    __syncthreads();
    if (tid < 2 * RAD + 1) wgt[tid] /= wsum;

    for (int i = tid; i < LR * LC; i += 256) {
        int r = i / LC, c = i % LC;
        int gy = symH(y0 - RAD - 1 + r);
        int gx = symW(x0 - RAD - 1 + c);
        in_t[r][c] = hm[((size_t)gy * W + gx) * NCH + ch];
    }
    __syncthreads();

    for (int i = tid; i < VRR * VC; i += 256) {
        int r = i / VC, c = i % VC;
        double acc = 0.0;
        #pragma unroll
        for (int t = 0; t < 2 * RAD + 1; t++)
            acc = fma(wgt[t], (double)in_t[r + t][c], acc);
        v[r][c] = acc;
    }
    __syncthreads();

    for (int i = tid; i < SR * SC; i += 256) {
        int r = i / SC, cc = i % SC;
        int gy = y0 - 1 + r;
        int gx = x0 - 1 + cc;
        double acc = 0.0;
        if (gy >= 0 && gy < H && gx >= 0 && gx < W) {
            #pragma unroll
            for (int t = 0; t < 2 * RAD + 1; t++)
                acc = fma(wgt[t], v[r][cc + t], acc);
        }
        smv[r][cc] = acc;
    }
    __syncthreads();

    for (int i = tid; i < TH * TW; i += 256) {
        int ly = i / TW, lx = i % TW;
        int gy = y0 + ly, gx = x0 + lx;
        if (gy >= H || gx >= W) continue;
        double s = smv[ly + 1][lx + 1];
        if (s > 0.1 &&
            s >= smv[ly][lx + 1] && s >= smv[ly + 2][lx + 1] &&
            s >= smv[ly + 1][lx] && s >= smv[ly + 1][lx + 2]) {
            float val = in_t[ly + RAD + 1][lx + RAD + 1];
            int pos = atomicAdd(&counters[ch], 1);
            if (pos < cap) {
                cval[(size_t)ch * cap + pos] = val;
                cidx[(size_t)ch * cap + pos] = gy * W + gx;
            }
        }
    }
}

// ---------------------------------------------------------------------------
// Kernel B: per-channel exact top-32 by (value desc, index asc)
// ---------------------------------------------------------------------------
#define BT 128
__global__ __launch_bounds__(BT) void topk_kernel(
    const float* __restrict__ cval, const int* __restrict__ cidx,
    const int* __restrict__ counters, int cap, float* __restrict__ out)
{
    __shared__ unsigned long long lk[KTOP * BT];
    __shared__ unsigned long long rk[BT];
    __shared__ int rw[BT];
    __shared__ int winner;

    const int tid = threadIdx.x;
    const int ch  = blockIdx.x;
    int n = counters[ch];
    if (n > cap) n = cap;

    int cnt = 0;
    for (int j = tid; j < n; j += BT) {
        float v = cval[(size_t)ch * cap + j];
        unsigned int u = __float_as_uint(v);
        u = (u & 0x80000000u) ? ~u : (u | 0x80000000u);
        unsigned long long key =
            ((unsigned long long)u << 32) |
            (unsigned int)(0xFFFFFFFFu - (unsigned int)cidx[(size_t)ch * cap + j]);
        if (cnt == KTOP) {
            if (key <= lk[(KTOP - 1) * BT + tid]) continue;
            cnt = KTOP - 1;
        }
        int i = cnt;
        while (i > 0 && key > lk[(i - 1) * BT + tid]) {
            lk[i * BT + tid] = lk[(i - 1) * BT + tid];
            i--;
        }
        lk[i * BT + tid] = key;
        cnt++;
    }
    int cur = 0;
    __syncthreads();

    for (int k = 0; k < KTOP; k++) {
        rk[tid] = (cur < cnt) ? lk[cur * BT + tid] : 0ULL;
        rw[tid] = tid;
        __syncthreads();
        for (int s = BT / 2; s > 0; s >>= 1) {
            if (tid < s) {
                if (rk[tid + s] > rk[tid]) { rk[tid] = rk[tid + s]; rw[tid] = rw[tid + s]; }
            }
            __syncthreads();
        }
        if (tid == 0) {
            winner = rw[0];
            unsigned long long bk = rk[0];
            float px, py, sc, mk;
            if (bk == 0ULL) {
                int fake = k - n; if (fake < 0) fake = 0;
                px = (float)(fake % W); py = (float)(fake / W); sc = 0.f; mk = 0.f;
            } else {
                unsigned int u = (unsigned int)(bk >> 32);
                unsigned int fb = (u & 0x80000000u) ? (u ^ 0x80000000u) : ~u;
                float v = __uint_as_float(fb);
                int idx = (int)(0xFFFFFFFFu - (unsigned int)(bk & 0xFFFFFFFFu));
                px = (float)(idx % W); py = (float)(idx / W); sc = v; mk = 1.f;
            }
            out[ch * KTOP + k]          = px;
            out[OFF_PY + ch * KTOP + k] = py;
            out[OFF_SC + ch * KTOP + k] = sc;
            out[OFF_MK + ch * KTOP + k] = mk;
        }
        __syncthreads();
        if (tid == winner && cur < cnt) cur++;
        __syncthreads();
    }
}

// ---------------------------------------------------------------------------
// Kernel C: limb connection scores (26 x 32 x 32)
// ---------------------------------------------------------------------------
__global__ __launch_bounds__(1024) void limbs_kernel(
    const float* __restrict__ pk, const float* __restrict__ paf,
    float* __restrict__ out)
{
    const int l = blockIdx.x;
    const int tid = threadIdx.x;
    const int i = tid >> 5;
    const int j = tid & 31;
    const int A = LIMBS_d[2 * l], B = LIMBS_d[2 * l + 1];

    float ax = pk[A * KTOP + i],          ay = pk[OFF_PY + A * KTOP + i];
    float ma = pk[OFF_MK + A * KTOP + i];
    float bx = pk[B * KTOP + j],          by = pk[OFF_PY + B * KTOP + j];
    float mb = pk[OFF_MK + B * KTOP + j];

    float vx = bx - ax, vy = by - ay;
    float norm = sqrtf(vx * vx + vy * vy) + 1e-10f;
    float ux = vx / norm, uy = vy / norm;

    const float step = 1.0f / 9.0f;
    float sum = 0.f;
    #pragma unroll
    for (int m = 0; m < MID; m++) {
        float t = (float)m * step;
        int sx = (int)rintf(ax + vx * t);
        int sy = (int)rintf(ay + vy * t);
        const float* p = paf + ((size_t)sy * W + sx) * (2 * NLIMB) + 2 * l;
        sum += p[0] * ux + p[1] * uy;
    }
    float score = sum / (float)MID;
    score = score < 0.f ? 0.f : (score > 1.f ? 1.f : score);
    float res = (ma != 0.f && mb != 0.f) ? score : 0.f;
    out[OFF_CONN + l * (KTOP * KTOP) + i * KTOP + j] = res;
}

// ---------------------------------------------------------------------------
extern "C" void kernel_launch(void* const* d_in, const int* in_sizes, int n_in,
                              void* d_out, int out_size, void* d_ws, size_t ws_size,
                              hipStream_t stream)
{
    const float* hm  = (const float*)d_in[0];
    const float* paf = (const float*)d_in[1];
    float* out = (float*)d_out;

    const size_t planar_bytes = (size_t)NPART * HWSZ * sizeof(float);  // ~207.4 MB
    const size_t head = 256;

    // Path A needs: counters + candidates(25*cap*8) + planar copy
    bool pathA = false;
    int cap = 1;
    if (ws_size > head + planar_bytes + (size_t)NPART * 8 * 4096) {
        size_t avail = ws_size - head - planar_bytes;
        long long c = (long long)(avail / ((size_t)NPART * 8));
        cap = c > 65536 ? 65536 : (int)c;
        pathA = true;
    } else {
        size_t avail = ws_size > head ? ws_size - head : 0;
        long long c = (long long)(avail / ((size_t)NPART * 8));
        cap = c > 65536 ? 65536 : (int)c;
        if (cap < 1) cap = 1;
    }

    int*   counters = (int*)d_ws;
    float* cval = (float*)((char*)d_ws + head);
    int*   cidx = (int*)(cval + (size_t)NPART * cap);
    float* planar = (float*)(cidx + (size_t)NPART * cap);
    // align planar to 256B
    planar = (float*)(((uintptr_t)planar + 255) & ~(uintptr_t)255);

    hipMemsetAsync(d_ws, 0, head, stream);

    if (pathA) {
        transpose_k<<<HWSZ / 256, 256, 0, stream>>>(hm, planar);
        dim3 gA(W / TW, (H + TH - 1) / TH, NPART);
        blur_peaks_planar<<<gA, 256, 0, stream>>>(planar, cval, cidx, counters, cap);
    } else {
        dim3 gA(NPART, (W + TW - 1) / TW, (H + TH - 1) / TH);
        blur_peaks_gather<<<gA, 256, 0, stream>>>(hm, cval, cidx, counters, cap);
    }
    topk_kernel<<<NPART, BT, 0, stream>>>(cval, cidx, counters, cap, out);
    limbs_kernel<<<NLIMB, 1024, 0, stream>>>(out, paf, out);
}

// Round 3
// 891.181 us; speedup vs baseline: 4.0615x; 4.0615x over previous
//
#include <hip/hip_runtime.h>
#include <math.h>
#include <float.h>

#define H 1080
#define W 1920
#define HWSZ (H*W)
#define NPART 25
#define NCH 26          // heatmap channels in memory (NPART+1)
#define NLIMB 26
#define KTOP 32
#define MID 10
#define RAD 12

// Tile geometry for fused blur+peak kernel
#define TH 32
#define TW 64
#define LRP 62               // padded input rows (58 needed)
#define LC  90               // input cols
#define VRR 34               // vertical-blur rows
#define VCP 93               // v cols padded to odd stride (bank spread for f64)
#define SR  34               // sm rows
#define SC  66               // sm cols (real)
#define SCP 68               // sm col stride

// Output layout (floats): px[25*32] py[25*32] score[25*32] mask[25*32] conn[26*32*32]
#define OFF_PY   800
#define OFF_SC   1600
#define OFF_MK   2400
#define OFF_CONN 3200

__device__ __constant__ int LIMBS_d[NLIMB * 2] = {
    1,8, 1,2, 1,5, 2,3, 3,4, 5,6, 6,7, 8,9, 9,10, 10,11, 8,12, 12,13, 13,14,
    1,0, 0,15, 15,16, 0,17, 0,18, 14,19, 19,20, 14,21, 11,22, 22,23, 11,24, 2,17, 5,18
};

__device__ __forceinline__ int symH(int y) {
    if (y < 0) return -1 - y;
    if (y >= H) return 2 * H - 1 - y;
    return y;
}
__device__ __forceinline__ int symW(int x) {
    if (x < 0) return -1 - x;
    if (x >= W) return 2 * W - 1 - x;
    return x;
}

// ---------------------------------------------------------------------------
// Kernel T: channels-last (H,W,26) -> 25 planar (H,W) f32 images (bit-exact copy)
// ---------------------------------------------------------------------------
__global__ __launch_bounds__(256) void transpose_k(
    const float* __restrict__ hm, float* __restrict__ planar)
{
    __shared__ float t[256][NCH + 1];   // stride 27 (odd) = conflict-free
    const int tid = threadIdx.x;
    const size_t base = (size_t)blockIdx.x * 256;   // pixel index
    const float* src = hm + base * NCH;
    for (int k = tid; k < 256 * NCH; k += 256) {
        t[k / NCH][k % NCH] = src[k];               // coalesced global read
    }
    __syncthreads();
    #pragma unroll
    for (int c = 0; c < NPART; c++)
        planar[(size_t)c * HWSZ + base + tid] = t[tid][c];  // coalesced write
}

// ---------------------------------------------------------------------------
// Kernel A: fused separable gaussian blur (f64 accumulation) + NMS peak detect
// on PLANAR input. Candidate emission is BLOCK-COMPACTED: LDS buffer + one
// global atomic per block (was: one wave-atomic per peak -> same-address
// cross-XCD serialization, the R2 3.2ms pathology).
// ---------------------------------------------------------------------------
__global__ __launch_bounds__(256) void blur_peaks_planar(
    const float* __restrict__ planar,
    float* __restrict__ cval, int* __restrict__ cidx,
    int* __restrict__ counters, int cap)
{
    union SA {
        float  in_t[LRP][LC];   // 22.3 KB — raw tile (consumed by vertical pass)
        double smv[SR][SCP];    // 18.5 KB — overlaid after vertical pass done
    };
    union SB {
        double v[VRR][VCP];     // 25.3 KB — live vertical->horizontal
        struct { float cv[TH * TW]; int ci[TH * TW]; } cand;  // 16 KB — peak emission
    };
    __shared__ SA sa;
    __shared__ SB sb;
    __shared__ double wgt[2 * RAD + 1];
    __shared__ double wsum;
    __shared__ int lcount;
    __shared__ int gbase;

    const int tid = threadIdx.x;
    const int ch  = blockIdx.z;
    const int x0  = blockIdx.x * TW;
    const int y0  = blockIdx.y * TH;
    const float* plane = planar + (size_t)ch * HWSZ;

    if (tid == 0) lcount = 0;

    // gaussian weights in f64 (identical computation to round-1 exact kernel)
    if (tid < 2 * RAD + 1) {
        double t = (double)(tid - RAD) / 3.0;
        wgt[tid] = exp(-0.5 * t * t);
    }
    __syncthreads();
    if (tid == 0) {
        double s = 0.0;
        for (int i = 0; i < 2 * RAD + 1; i++) s += wgt[i];
        wsum = s;
    }
    __syncthreads();
    if (tid < 2 * RAD + 1) wgt[tid] /= wsum;

    // load input tile (coalesced planar rows, symmetric padding)
    for (int i = tid; i < LRP * LC; i += 256) {
        int r = i / LC, c = i % LC;
        int gy = symH(y0 - RAD - 1 + r);
        int gx = symW(x0 - RAD - 1 + c);
        sa.in_t[r][c] = plane[(size_t)gy * W + gx];
    }
    __syncthreads();   // also covers wgt normalization

    // vertical pass: 9 row-groups of 4 x 90 cols; sliding-window register reuse
    for (int seg = tid; seg < 9 * LC; seg += 256) {
        int c  = seg % LC;            // consecutive lanes -> consecutive cols
        int r0 = (seg / LC) * 4;
        double a0 = 0, a1 = 0, a2 = 0, a3 = 0;
        #pragma unroll
        for (int t = 0; t < 28; t++) {
            double x = (double)sa.in_t[r0 + t][c];
            if (t < 25)            a0 = fma(wgt[t],     x, a0);
            if (t >= 1 && t < 26)  a1 = fma(wgt[t - 1], x, a1);
            if (t >= 2 && t < 27)  a2 = fma(wgt[t - 2], x, a2);
            if (t >= 3)            a3 = fma(wgt[t - 3], x, a3);
        }
        sb.v[r0][c] = a0;
        if (r0 + 1 < VRR) sb.v[r0 + 1][c] = a1;
        if (r0 + 2 < VRR) sb.v[r0 + 2][c] = a2;
        if (r0 + 3 < VRR) sb.v[r0 + 3][c] = a3;
    }
    __syncthreads();   // in_t fully consumed; smv may overlay it now

    // horizontal pass: 17 col-groups of 4 x 34 rows; r fastest (bank spread)
    for (int seg = tid; seg < 17 * SR; seg += 256) {
        int r   = seg % SR;
        int cc0 = (seg / SR) * 4;
        int gy  = y0 - 1 + r;
        double a0 = 0, a1 = 0, a2 = 0, a3 = 0;
        #pragma unroll
        for (int t = 0; t < 28; t++) {
            double x = sb.v[r][cc0 + t];
            if (t < 25)            a0 = fma(wgt[t],     x, a0);
            if (t >= 1 && t < 26)  a1 = fma(wgt[t - 1], x, a1);
            if (t >= 2 && t < 27)  a2 = fma(wgt[t - 2], x, a2);
            if (t >= 3)            a3 = fma(wgt[t - 3], x, a3);
        }
        bool rowok = (gy >= 0 && gy < H);
        { int cc = cc0;     if (cc < SC) { int gx = x0 - 1 + cc; sa.smv[r][cc] = (rowok && gx >= 0 && gx < W) ? a0 : 0.0; } }
        { int cc = cc0 + 1; if (cc < SC) { int gx = x0 - 1 + cc; sa.smv[r][cc] = (rowok && gx >= 0 && gx < W) ? a1 : 0.0; } }
        { int cc = cc0 + 2; if (cc < SC) { int gx = x0 - 1 + cc; sa.smv[r][cc] = (rowok && gx >= 0 && gx < W) ? a2 : 0.0; } }
        { int cc = cc0 + 3; if (cc < SC) { int gx = x0 - 1 + cc; sa.smv[r][cc] = (rowok && gx >= 0 && gx < W) ? a3 : 0.0; } }
    }
    __syncthreads();   // v fully consumed; cand may overlay it now

    // peak detection -> LDS-compacted candidates (fast per-CU LDS atomics)
    for (int i = tid; i < TH * TW; i += 256) {
        int ly = i >> 6, lx = i & 63;
        int gy = y0 + ly, gx = x0 + lx;
        if (gy >= H) continue;          // W = 30*64 exactly; only y can overhang
        double s = sa.smv[ly + 1][lx + 1];
        if (s > 0.1 &&
            s >= sa.smv[ly][lx + 1] && s >= sa.smv[ly + 2][lx + 1] &&
            s >= sa.smv[ly + 1][lx] && s >= sa.smv[ly + 1][lx + 2]) {
            float val = plane[(size_t)gy * W + gx];   // exact original bits
            int pos = atomicAdd(&lcount, 1);          // LDS atomic
            sb.cand.cv[pos] = val;                    // pos < 2048 by construction
            sb.cand.ci[pos] = gy * W + gx;
        }
    }
    __syncthreads();

    // one global atomic per block, then coalesced copy-out
    if (tid == 0) gbase = atomicAdd(&counters[ch], lcount);
    __syncthreads();
    int n = lcount, b = gbase;
    for (int i = tid; i < n; i += 256) {
        int p = b + i;
        if (p < cap) {
            cval[(size_t)ch * cap + p] = sb.cand.cv[i];
            cidx[(size_t)ch * cap + p] = sb.cand.ci[i];
        }
    }
}

// ---------------------------------------------------------------------------
// Kernel A-fallback: round-1 gather version (used only if ws too small)
// ---------------------------------------------------------------------------
#define LR (TH + 2*RAD + 2)
#define VC (TW + 2*RAD + 2)
__global__ __launch_bounds__(256) void blur_peaks_gather(
    const float* __restrict__ hm,
    float* __restrict__ cval, int* __restrict__ cidx,
    int* __restrict__ counters, int cap)
{
    __shared__ float  in_t[LR][LC];
    __shared__ double v[VRR][VC];
    __shared__ double smv[SR][SC];
    __shared__ double wgt[2 * RAD + 1];
    __shared__ double wsum;

    const int tid = threadIdx.x;
    const int ch  = blockIdx.x;
    const int x0  = blockIdx.y * TW;
    const int y0  = blockIdx.z * TH;

    if (tid < 2 * RAD + 1) {
        double t = (double)(tid - RAD) / 3.0;
        wgt[tid] = exp(-0.5 * t * t);
    }
    __syncthreads();
    if (tid == 0) {
        double s = 0.0;
        for (int i = 0; i < 2 * RAD + 1; i++) s += wgt[i];
        wsum = s;
    }
    __syncthreads();
    if (tid < 2 * RAD + 1) wgt[tid] /= wsum;

    for (int i = tid; i < LR * LC; i += 256) {
        int r = i / LC, c = i % LC;
        int gy = symH(y0 - RAD - 1 + r);
        int gx = symW(x0 - RAD - 1 + c);
        in_t[r][c] = hm[((size_t)gy * W + gx) * NCH + ch];
    }
    __syncthreads();

    for (int i = tid; i < VRR * VC; i += 256) {
        int r = i / VC, c = i % VC;
        double acc = 0.0;
        #pragma unroll
        for (int t = 0; t < 2 * RAD + 1; t++)
            acc = fma(wgt[t], (double)in_t[r + t][c], acc);
        v[r][c] = acc;
    }
    __syncthreads();

    for (int i = tid; i < SR * SC; i += 256) {
        int r = i / SC, cc = i % SC;
        int gy = y0 - 1 + r;
        int gx = x0 - 1 + cc;
        double acc = 0.0;
        if (gy >= 0 && gy < H && gx >= 0 && gx < W) {
            #pragma unroll
            for (int t = 0; t < 2 * RAD + 1; t++)
                acc = fma(wgt[t], v[r][cc + t], acc);
        }
        smv[r][cc] = acc;
    }
    __syncthreads();

    for (int i = tid; i < TH * TW; i += 256) {
        int ly = i / TW, lx = i % TW;
        int gy = y0 + ly, gx = x0 + lx;
        if (gy >= H || gx >= W) continue;
        double s = smv[ly + 1][lx + 1];
        if (s > 0.1 &&
            s >= smv[ly][lx + 1] && s >= smv[ly + 2][lx + 1] &&
            s >= smv[ly + 1][lx] && s >= smv[ly + 1][lx + 2]) {
            float val = in_t[ly + RAD + 1][lx + RAD + 1];
            int pos = atomicAdd(&counters[ch], 1);
            if (pos < cap) {
                cval[(size_t)ch * cap + pos] = val;
                cidx[(size_t)ch * cap + pos] = gy * W + gx;
            }
        }
    }
}

// ---------------------------------------------------------------------------
// Kernel B: per-channel exact top-32 by (value desc, index asc)
// ---------------------------------------------------------------------------
#define BT 128
__global__ __launch_bounds__(BT) void topk_kernel(
    const float* __restrict__ cval, const int* __restrict__ cidx,
    const int* __restrict__ counters, int cap, float* __restrict__ out)
{
    __shared__ unsigned long long lk[KTOP * BT];
    __shared__ unsigned long long rk[BT];
    __shared__ int rw[BT];
    __shared__ int winner;

    const int tid = threadIdx.x;
    const int ch  = blockIdx.x;
    int n = counters[ch];
    if (n > cap) n = cap;

    int cnt = 0;
    for (int j = tid; j < n; j += BT) {
        float v = cval[(size_t)ch * cap + j];
        unsigned int u = __float_as_uint(v);
        u = (u & 0x80000000u) ? ~u : (u | 0x80000000u);
        unsigned long long key =
            ((unsigned long long)u << 32) |
            (unsigned int)(0xFFFFFFFFu - (unsigned int)cidx[(size_t)ch * cap + j]);
        if (cnt == KTOP) {
            if (key <= lk[(KTOP - 1) * BT + tid]) continue;
            cnt = KTOP - 1;
        }
        int i = cnt;
        while (i > 0 && key > lk[(i - 1) * BT + tid]) {
            lk[i * BT + tid] = lk[(i - 1) * BT + tid];
            i--;
        }
        lk[i * BT + tid] = key;
        cnt++;
    }
    int cur = 0;
    __syncthreads();

    for (int k = 0; k < KTOP; k++) {
        rk[tid] = (cur < cnt) ? lk[cur * BT + tid] : 0ULL;
        rw[tid] = tid;
        __syncthreads();
        for (int s = BT / 2; s > 0; s >>= 1) {
            if (tid < s) {
                if (rk[tid + s] > rk[tid]) { rk[tid] = rk[tid + s]; rw[tid] = rw[tid + s]; }
            }
            __syncthreads();
        }
        if (tid == 0) {
            winner = rw[0];
            unsigned long long bk = rk[0];
            float px, py, sc, mk;
            if (bk == 0ULL) {
                int fake = k - n; if (fake < 0) fake = 0;
                px = (float)(fake % W); py = (float)(fake / W); sc = 0.f; mk = 0.f;
            } else {
                unsigned int u = (unsigned int)(bk >> 32);
                unsigned int fb = (u & 0x80000000u) ? (u ^ 0x80000000u) : ~u;
                float v = __uint_as_float(fb);
                int idx = (int)(0xFFFFFFFFu - (unsigned int)(bk & 0xFFFFFFFFu));
                px = (float)(idx % W); py = (float)(idx / W); sc = v; mk = 1.f;
            }
            out[ch * KTOP + k]          = px;
            out[OFF_PY + ch * KTOP + k] = py;
            out[OFF_SC + ch * KTOP + k] = sc;
            out[OFF_MK + ch * KTOP + k] = mk;
        }
        __syncthreads();
        if (tid == winner && cur < cnt) cur++;
        __syncthreads();
    }
}

// ---------------------------------------------------------------------------
// Kernel C: limb connection scores (26 x 32 x 32)
// ---------------------------------------------------------------------------
__global__ __launch_bounds__(1024) void limbs_kernel(
    const float* __restrict__ pk, const float* __restrict__ paf,
    float* __restrict__ out)
{
    const int l = blockIdx.x;
    const int tid = threadIdx.x;
    const int i = tid >> 5;
    const int j = tid & 31;
    const int A = LIMBS_d[2 * l], B = LIMBS_d[2 * l + 1];

    float ax = pk[A * KTOP + i],          ay = pk[OFF_PY + A * KTOP + i];
    float ma = pk[OFF_MK + A * KTOP + i];
    float bx = pk[B * KTOP + j],          by = pk[OFF_PY + B * KTOP + j];
    float mb = pk[OFF_MK + B * KTOP + j];

    float vx = bx - ax, vy = by - ay;
    float norm = sqrtf(vx * vx + vy * vy) + 1e-10f;
    float ux = vx / norm, uy = vy / norm;

    const float step = 1.0f / 9.0f;
    float sum = 0.f;
    #pragma unroll
    for (int m = 0; m < MID; m++) {
        float t = (float)m * step;
        int sx = (int)rintf(ax + vx * t);
        int sy = (int)rintf(ay + vy * t);
        const float* p = paf + ((size_t)sy * W + sx) * (2 * NLIMB) + 2 * l;
        sum += p[0] * ux + p[1] * uy;
    }
    float score = sum / (float)MID;
    score = score < 0.f ? 0.f : (score > 1.f ? 1.f : score);
    float res = (ma != 0.f && mb != 0.f) ? score : 0.f;
    out[OFF_CONN + l * (KTOP * KTOP) + i * KTOP + j] = res;
}

// ---------------------------------------------------------------------------
extern "C" void kernel_launch(void* const* d_in, const int* in_sizes, int n_in,
                              void* d_out, int out_size, void* d_ws, size_t ws_size,
                              hipStream_t stream)
{
    const float* hm  = (const float*)d_in[0];
    const float* paf = (const float*)d_in[1];
    float* out = (float*)d_out;

    const size_t planar_bytes = (size_t)NPART * HWSZ * sizeof(float);  // ~207.4 MB
    const size_t head = 256;

    bool pathA = false;
    int cap = 1;
    if (ws_size > head + planar_bytes + (size_t)NPART * 8 * 4096) {
        size_t avail = ws_size - head - planar_bytes;
        long long c = (long long)(avail / ((size_t)NPART * 8));
        cap = c > 65536 ? 65536 : (int)c;
        pathA = true;
    } else {
        size_t avail = ws_size > head ? ws_size - head : 0;
        long long c = (long long)(avail / ((size_t)NPART * 8));
        cap = c > 65536 ? 65536 : (int)c;
        if (cap < 1) cap = 1;
    }

    int*   counters = (int*)d_ws;
    float* cval = (float*)((char*)d_ws + head);
    int*   cidx = (int*)(cval + (size_t)NPART * cap);
    float* planar = (float*)(cidx + (size_t)NPART * cap);
    planar = (float*)(((uintptr_t)planar + 255) & ~(uintptr_t)255);

    hipMemsetAsync(d_ws, 0, head, stream);

    if (pathA) {
        transpose_k<<<HWSZ / 256, 256, 0, stream>>>(hm, planar);
        dim3 gA(W / TW, (H + TH - 1) / TH, NPART);
        blur_peaks_planar<<<gA, 256, 0, stream>>>(planar, cval, cidx, counters, cap);
    } else {
        dim3 gA(NPART, (W + TW - 1) / TW, (H + TH - 1) / TH);
        blur_peaks_gather<<<gA, 256, 0, stream>>>(hm, cval, cidx, counters, cap);
    }
    topk_kernel<<<NPART, BT, 0, stream>>>(cval, cidx, counters, cap, out);
    limbs_kernel<<<NLIMB, 1024, 0, stream>>>(out, paf, out);
}